// Round 7
// baseline (171.172 us; speedup 1.0000x reference)
//
#include <hip/hip_runtime.h>
#include <math.h>

// RWKV WKV forward — v7: v6 two-kernel skeleton + explicit register prefetch.
// B=8, T=2048, H=768. T split into NQ=8 quarters of 256; each quarter has
// NCB=32 chunks of L=8.
// Block = (h-slice of 32h, quarter q, batch b): 32 chunks x 8 float4-groups
// = 256 threads. Grid = (24, 8, 8) = 1536 blocks -> 6 blocks/CU offered.
// KEY FIX vs v6 (k1 was latency-bound, VGPR=28, loads sunk to use sites):
// the whole chunk (8 x k-float4 + 8 x v-float4 = 64 VGPRs) is loaded into
// register arrays BEFORE compute — 256 B/lane in flight, one HBM latency
// exposure per chunk. Blocks span 32h = full 128B lines (no over-fetch).
// k1: chunk aggregates + depth-5 LDS scan; store per-chunk local exclusive
//     prefixes + per-quarter totals to d_ws (~19 MB).
// k2: incoming = fold(totals q'<q, shifted by w*256 each) ⊕ local exclusive
//     (shifted by w*8*c), prefetch chunk, replay 8 steps, write out.

#define B_    8
#define T_    2048
#define H_    768
#define H4_   (H_/4)          // 192
#define NQ_   8
#define NCB_  32              // chunks per block
#define L_    8
#define QLEN_ (NCB_*L_)       // 256
#define HS_   (H_/32)         // 24 h-slices
#define HO4_  8
#define NT_   256
#define PAD_  33

#define EXCL_N ((size_t)B_*HS_*NQ_*NCB_*32)   // 1572864 floats per array
#define TOT_N  ((size_t)B_*HS_*NQ_*32)        // 49152 floats per array

// ---------------- k1: aggregates + block scan + store prefixes ----------------
__global__ __launch_bounds__(NT_) void wkv_p1(
    const float* __restrict__ key, const float* __restrict__ val,
    const float* __restrict__ time_decay,
    float* __restrict__ ea, float* __restrict__ eb, float* __restrict__ ee,
    float* __restrict__ ta, float* __restrict__ tb, float* __restrict__ te)
{
    __shared__ float sa[NCB_][PAD_];   // 3 * 32*33*4B = 12.7 KB
    __shared__ float sb[NCB_][PAD_];
    __shared__ float se[NCB_][PAD_];

    const int tid = threadIdx.x;
    const int ho4 = tid & (HO4_ - 1);
    const int c   = tid >> 3;          // 0..31 local chunk
    const int col = ho4 * 4;
    const int hs  = blockIdx.x;
    const int q   = blockIdx.y;
    const int b   = blockIdx.z;
    const int h0  = hs * 32 + col;

    const float4 td4 = *(const float4*)(time_decay + h0);
    float w[4];
    w[0] = -__expf(td4.x); w[1] = -__expf(td4.y);
    w[2] = -__expf(td4.z); w[3] = -__expf(td4.w);

    const int cg = q * NCB_ + c;
    const size_t base = ((size_t)b * T_ + (size_t)cg * L_) * H_ + h0;
    const float4* kp = (const float4*)(key + base);
    const float4* vp = (const float4*)(val + base);

    // ---- register prefetch of the whole chunk (the in-flight buffer) ----
    float4 kr[L_], vr[L_];
#pragma unroll
    for (int t = 0; t < L_; ++t) {
        kr[t] = kp[(size_t)t * H4_];
        vr[t] = vp[(size_t)t * H4_];
    }

    float a[4]  = {0.f, 0.f, 0.f, 0.f};
    float bb[4] = {0.f, 0.f, 0.f, 0.f};
    float e[4]  = {-INFINITY, -INFINITY, -INFINITY, -INFINITY};

#pragma unroll
    for (int t = 0; t < L_; ++t) {
        const float kt[4] = {kr[t].x, kr[t].y, kr[t].z, kr[t].w};
        const float vt[4] = {vr[t].x, vr[t].y, vr[t].z, vr[t].w};
#pragma unroll
        for (int j = 0; j < 4; ++j) {
            const float ew = e[j] + w[j];
            const float m2 = fmaxf(ew, kt[j]);
            const float s1 = __expf(ew - m2);
            const float s2 = __expf(kt[j] - m2);
            a[j]  = fmaf(s1, a[j],  s2 * vt[j]);
            bb[j] = fmaf(s1, bb[j], s2);
            e[j]  = m2;
        }
    }

    // depth-5 inclusive scan over the block's 32 chunks (single LDS buffer)
#pragma unroll
    for (int j = 0; j < 4; ++j) {
        sa[c][col + j] = a[j];
        sb[c][col + j] = bb[j];
        se[c][col + j] = e[j];
    }
    __syncthreads();

#pragma unroll
    for (int s = 0; s < 5; ++s) {
        const int d = 1 << s;
        const bool act = (c >= d);
        float pa[4], pb[4], pe[4];
        if (act) {
#pragma unroll
            for (int j = 0; j < 4; ++j) {
                pa[j] = sa[c - d][col + j];
                pb[j] = sb[c - d][col + j];
                pe[j] = se[c - d][col + j] + w[j] * (float)(L_ * d);
            }
        }
        __syncthreads();
        if (act) {
#pragma unroll
            for (int j = 0; j < 4; ++j) {
                const float m = fmaxf(pe[j], e[j]);
                const float x = __expf(pe[j] - m);
                const float y = __expf(e[j] - m);
                a[j]  = fmaf(pa[j], x, a[j] * y);
                bb[j] = fmaf(pb[j], x, bb[j] * y);
                e[j]  = m;
                sa[c][col + j] = a[j];
                sb[c][col + j] = bb[j];
                se[c][col + j] = e[j];
            }
        }
        __syncthreads();
    }

    // local exclusive prefix (identity for c==0)
    float xa[4] = {0.f, 0.f, 0.f, 0.f};
    float xb[4] = {0.f, 0.f, 0.f, 0.f};
    float xe[4] = {-INFINITY, -INFINITY, -INFINITY, -INFINITY};
    if (c > 0) {
#pragma unroll
        for (int j = 0; j < 4; ++j) {
            xa[j] = sa[c - 1][col + j];
            xb[j] = sb[c - 1][col + j];
            xe[j] = se[c - 1][col + j];
        }
    }

    const size_t eoff = ((((size_t)b * HS_ + hs) * NQ_ + q) * NCB_ + c) * 32 + col;
#pragma unroll
    for (int j = 0; j < 4; ++j) {
        ea[eoff + j] = xa[j];
        eb[eoff + j] = xb[j];
        ee[eoff + j] = xe[j];
    }
    if (c == NCB_ - 1) {   // registers hold the inclusive total of the quarter
        const size_t toff = (((size_t)b * HS_ + hs) * NQ_ + q) * 32 + col;
#pragma unroll
        for (int j = 0; j < 4; ++j) {
            ta[toff + j] = a[j];
            tb[toff + j] = bb[j];
            te[toff + j] = e[j];
        }
    }
}

// ---------------- k2: fold prefixes + replay + emit --------------------------
__global__ __launch_bounds__(NT_) void wkv_p2(
    const float* __restrict__ key, const float* __restrict__ val,
    const float* __restrict__ time_decay, const float* __restrict__ time_first,
    const float* __restrict__ ea, const float* __restrict__ eb,
    const float* __restrict__ ee,
    const float* __restrict__ ta, const float* __restrict__ tb,
    const float* __restrict__ te,
    float* __restrict__ out)
{
    const int tid = threadIdx.x;
    const int ho4 = tid & (HO4_ - 1);
    const int c   = tid >> 3;
    const int col = ho4 * 4;
    const int hs  = blockIdx.x;
    const int q   = blockIdx.y;
    const int b   = blockIdx.z;
    const int h0  = hs * 32 + col;

    const int cg = q * NCB_ + c;
    const size_t base = ((size_t)b * T_ + (size_t)cg * L_) * H_ + h0;
    const float4* kp = (const float4*)(key + base);
    const float4* vp = (const float4*)(val + base);

    // ---- register prefetch of the whole chunk (issued FIRST, used last) ----
    float4 kr[L_], vr[L_];
#pragma unroll
    for (int t = 0; t < L_; ++t) {
        kr[t] = kp[(size_t)t * H4_];
        vr[t] = vp[(size_t)t * H4_];
    }

    const float4 td4 = *(const float4*)(time_decay + h0);
    const float4 tf4 = *(const float4*)(time_first + h0);
    float w[4], u[4];
    w[0] = -__expf(td4.x); w[1] = -__expf(td4.y);
    w[2] = -__expf(td4.z); w[3] = -__expf(td4.w);
    u[0] = tf4.x; u[1] = tf4.y; u[2] = tf4.z; u[3] = tf4.w;

    // own local exclusive prefix
    const size_t eoff = ((((size_t)b * HS_ + hs) * NQ_ + q) * NCB_ + c) * 32 + col;
    float ra[4], rb[4], re[4];
#pragma unroll
    for (int j = 0; j < 4; ++j) {
        ra[j] = ea[eoff + j];
        rb[j] = eb[eoff + j];
        re[j] = ee[eoff + j];
    }

    // fold quarter totals q' = 0..q-1 (uniform per block; at most 7 folds)
    float pa[4] = {0.f, 0.f, 0.f, 0.f};
    float pb[4] = {0.f, 0.f, 0.f, 0.f};
    float pe[4] = {-INFINITY, -INFINITY, -INFINITY, -INFINITY};
    for (int qq = 0; qq < q; ++qq) {
        const size_t toff = (((size_t)b * HS_ + hs) * NQ_ + qq) * 32 + col;
#pragma unroll
        for (int j = 0; j < 4; ++j) {
            const float Ta = ta[toff + j];
            const float Tb = tb[toff + j];
            const float Te = te[toff + j];
            const float sh = pe[j] + w[j] * (float)QLEN_;  // -inf stays -inf
            const float m  = fmaxf(sh, Te);                // finite (Te finite)
            const float x  = __expf(sh - m);
            const float y  = __expf(Te - m);
            pa[j] = fmaf(pa[j], x, Ta * y);
            pb[j] = fmaf(pb[j], x, Tb * y);
            pe[j] = m;
        }
    }

    // incoming state = combine(P shifted by c*L_, local exclusive)
#pragma unroll
    for (int j = 0; j < 4; ++j) {
        const float sh = pe[j] + w[j] * (float)(c * L_);
        const float m  = fmaxf(sh, re[j]);
        if (m > -INFINITY) {           // guard -inf minus -inf (q==0 && c==0)
            const float x = __expf(sh - m);
            const float y = __expf(re[j] - m);
            ra[j] = fmaf(pa[j], x, ra[j] * y);
            rb[j] = fmaf(pb[j], x, rb[j] * y);
            re[j] = m;
        }
    }

    float4* op = (float4*)(out + base);
#pragma unroll
    for (int t = 0; t < L_; ++t) {
        const float kt[4] = {kr[t].x, kr[t].y, kr[t].z, kr[t].w};
        const float vt[4] = {vr[t].x, vr[t].y, vr[t].z, vr[t].w};
        float o[4];
#pragma unroll
        for (int j = 0; j < 4; ++j) {
            // output at this timestep (state BEFORE update)
            const float uk = u[j] + kt[j];
            const float m1 = fmaxf(re[j], uk);
            const float wt = __expf(uk - m1);
            const float sc = __expf(re[j] - m1);
            const float num = fmaf(ra[j], sc, wt * vt[j]);
            const float den = fmaf(rb[j], sc, wt);
            o[j] = __fdividef(num, den);

            // state update
            const float ew = re[j] + w[j];
            const float m2 = fmaxf(ew, kt[j]);
            const float s1 = __expf(ew - m2);
            const float s2 = __expf(kt[j] - m2);
            ra[j] = fmaf(s1, ra[j], s2 * vt[j]);
            rb[j] = fmaf(s1, rb[j], s2);
            re[j] = m2;
        }
        float4 o4;
        o4.x = o[0]; o4.y = o[1]; o4.z = o[2]; o4.w = o[3];
        op[(size_t)t * H4_] = o4;
    }
}

extern "C" void kernel_launch(void* const* d_in, const int* in_sizes, int n_in,
                              void* d_out, int out_size, void* d_ws, size_t ws_size,
                              hipStream_t stream) {
    const float* key = (const float*)d_in[0];
    const float* val = (const float*)d_in[1];
    const float* td  = (const float*)d_in[2];
    const float* tf  = (const float*)d_in[3];
    float* out = (float*)d_out;

    float* ea = (float*)d_ws;
    float* eb = ea + EXCL_N;
    float* ee = eb + EXCL_N;
    float* ta = ee + EXCL_N;
    float* tb = ta + TOT_N;
    float* te = tb + TOT_N;   // total: 3*1572864 + 3*49152 floats = 19.5 MB

    dim3 grid(HS_, NQ_, B_);  // (24, 8, 8) = 1536 blocks, 256 threads each
    wkv_p1<<<grid, NT_, 0, stream>>>(key, val, td, ea, eb, ee, ta, tb, te);
    wkv_p2<<<grid, NT_, 0, stream>>>(key, val, td, tf, ea, eb, ee, ta, tb, te, out);
}